// Round 10
// baseline (27935.049 us; speedup 1.0000x reference)
//
#include <hip/hip_runtime.h>
#include <hip/hip_fp16.h>
#include <stdint.h>

// Problem dims
#define B_    64
#define T_    2048
#define IN_   64
#define H_    512
#define H2_   1024
#define OUT_  32
#define KTOT  576          // IN_ + H_

// Grid: 128 blocks = 4 bg-PAIRS x 32 col-groups, 256 threads.
// Round-9 lesson: >128-VGPR kernels get exactly 1 block/CU resident
// (occupancy 12%); a 512-block grid SERIALIZED into two halves (26.3ms =
// 2 x 13.15). Cross-block TLP is unreachable -> hide barrier latency
// WITHIN the block: each block serves TWO batch-groups (bg0=2p, bg1=2p+1,
// same column slice -> SAME weights, no VGPR cost) and alternates
// A(bg0) A(bg1) B(bg0) B(bg1), so every barrier wait is covered by a full
// compute slot of the other bg issued after that barrier's bump.
// Round-9 datum: compute ~0.5us/step, sync ~6us/step -> interleave targets
// the 6.
#define NBG   8
#define NCG   32           // col-groups per bg (barrier fan-in)
#define NTHR  256
#define BPG   8            // batches per group
#define KSL   18           // k per slice (32 slices x 18 = 576)
#define RS    12           // bufA row stride in floats

// ws layout (32-bit words) -- round-7 verbatim
#define ABORT_IDX   0
#define CTR_OFF     1024                 // first counter, word offset (4KB)
#define CTR_STRIDE  1024                 // 4KB between counters
#define NCTR        (NBG * 2)            // 16 counters
#define BUF_BASE    (CTR_OFF + NCTR * CTR_STRIDE)   // 17408
#define XSLABW      16384    // 32-bit words per fp16 slab: 8*512*8*2B / 4

// ---- fp16 pack/unpack ----
__device__ __forceinline__ unsigned f2h2(float a, float b) {
  __half2 h = __floats2half2_rn(a, b);   // lo = a, hi = b
  unsigned r; __builtin_memcpy(&r, &h, 4); return r;
}
__device__ __forceinline__ float2 h2f2(unsigned u) {
  __half2 h; __builtin_memcpy(&h, &u, 4);
  return __half22float2(h);              // x = lo, y = hi
}

// ---- MALL-resident exchange primitives (round-7 proven) ----
// Publish packed fp16 pair: 4B atomic swap at the MALL (sc1), drained
// immediately (round-6 lesson: drain before bump, nothing between).
__device__ __forceinline__ void gpubh(unsigned* p, unsigned v) {
  asm volatile("global_atomic_swap %0, %1, off sc1\n\ts_waitcnt vmcnt(0)"
               :: "v"(p), "v"(v) : "memory");
}
// Counter bump: fire-and-forget one-way add at the MALL.
__device__ __forceinline__ void gaddu(unsigned* p, unsigned v) {
  asm volatile("global_atomic_add %0, %1, off sc1"
               :: "v"(p), "v"(v) : "memory");
}
// Coherent 4B poll load.
__device__ __forceinline__ unsigned gpollu(const unsigned* p) {
  unsigned v;
  asm volatile("global_load_dword %0, %1, off sc0 sc1\n\ts_waitcnt vmcnt(0)"
               : "=v"(v) : "v"(p) : "memory");
  return v;
}
// Consume: two MALL-coherent 16B loads (one col x 8 batches fp16 each).
__device__ __forceinline__ void gload2(const unsigned* p0, const unsigned* p1,
                                       uint4& a, uint4& b) {
  asm volatile(
      "global_load_dwordx4 %0, %2, off sc0 sc1\n\t"
      "global_load_dwordx4 %1, %3, off sc0 sc1\n\t"
      "s_waitcnt vmcnt(0)"
      : "=&v"(a), "=&v"(b)
      : "v"(p0), "v"(p1)
      : "memory");
}

__global__ __launch_bounds__(256) void gru_init(float* ws, const float* __restrict__ x0) {
  int i = blockIdx.x * blockDim.x + threadIdx.x;
  int stride = gridDim.x * blockDim.x;
  unsigned* w = (unsigned*)ws;
  for (int k = i; k < BUF_BASE; k += stride) w[k] = 0u;   // abort + counters
  // xg0 slab (fp16): word p = (bg*512 + col)*4 + (b>>1)
  unsigned* xh = w + BUF_BASE;
  for (int p = i; p < NBG * H_ * 4; p += stride) {
    int bg = p >> 11, col = (p >> 2) & (H_ - 1), f2 = p & 3;
    float v0 = x0[(bg * 8 + 2 * f2) * H_ + col];
    float v1 = x0[(bg * 8 + 2 * f2 + 1) * H_ + col];
    xh[p] = f2h2(v0, v1);
  }
}

// Wait: ONE lane polls ONE 4KB-isolated counter word until it reaches target.
__device__ __forceinline__ bool gbar_wait(unsigned* ctr, unsigned target,
                                          unsigned* abort_w) {
  __shared__ int s_ok;
  if (threadIdx.x == 0) {
    int ok = 1;
    int polls = 0;
    while (gpollu(ctr) < target) {
      __builtin_amdgcn_s_sleep(1);
      if ((++polls & 255) == 0) {
        if (__hip_atomic_load(abort_w, __ATOMIC_RELAXED, __HIP_MEMORY_SCOPE_AGENT) != 0u ||
            polls > 2000000) {
          __hip_atomic_store(abort_w, 1u, __ATOMIC_RELAXED, __HIP_MEMORY_SCOPE_AGENT);
          ok = 0;
          break;
        }
      }
    }
    s_ok = ok;
  }
  __syncthreads();
  __atomic_signal_fence(__ATOMIC_ACQUIRE);  // compiler reordering guard only
  return s_ok != 0;
}

// ---- phase macros (macros, not functions: keep weight arrays reg-promoted) ----
#define PHASE_A(BG, BUF, ZREG, XOLDZ, CTRA, CTRB)                             \
  {                                                                           \
    if (!gbar_wait(CTRB, (unsigned)(NCG * t), abort_w)) return;               \
    {                                                                         \
      const unsigned* s0 = xcur + ((size_t)((BG) * H_) + tid) * 4;            \
      const unsigned* s1 = xcur + ((size_t)((BG) * H_) + tid + 256) * 4;      \
      uint4 a, b;                                                             \
      gload2(s0, s1, a, b);                                                   \
      float2 c0 = h2f2(a.x), c1 = h2f2(a.y), c2 = h2f2(a.z), c3 = h2f2(a.w);  \
      *(float4*)&BUF[(64 + tid) * RS]     = make_float4(c0.x, c0.y, c1.x, c1.y); \
      *(float4*)&BUF[(64 + tid) * RS + 4] = make_float4(c2.x, c2.y, c3.x, c3.y); \
      float2 d0 = h2f2(b.x), d1 = h2f2(b.y), d2 = h2f2(b.z), d3 = h2f2(b.w);  \
      *(float4*)&BUF[(64 + tid + 256) * RS]     = make_float4(d0.x, d0.y, d1.x, d1.y); \
      *(float4*)&BUF[(64 + tid + 256) * RS + 4] = make_float4(d2.x, d2.y, d3.x, d3.y); \
    }                                                                         \
    __syncthreads();                                                          \
    float acc[4][8] = {};                                                     \
    _Pragma("unroll")                                                         \
    for (int i = 0; i < KSL; ++i) {                                           \
      const float* xr = &BUF[(kb + i) * RS];                                  \
      float4 x0v = *(const float4*)xr;                                        \
      float4 x1v = *(const float4*)(xr + 4);                                  \
      _Pragma("unroll")                                                       \
      for (int m = 0; m < 4; ++m) {                                           \
        float wv = wA[i][m];                                                  \
        acc[m][0] += wv * x0v.x; acc[m][1] += wv * x0v.y;                     \
        acc[m][2] += wv * x0v.z; acc[m][3] += wv * x0v.w;                     \
        acc[m][4] += wv * x1v.x; acc[m][5] += wv * x1v.y;                     \
        acc[m][6] += wv * x1v.z; acc[m][7] += wv * x1v.w;                     \
      }                                                                       \
    }                                                                         \
    _Pragma("unroll")                                                         \
    for (int m = 0; m < 4; ++m)                                               \
      _Pragma("unroll")                                                       \
      for (int b = 0; b < 8; ++b) {                                           \
        acc[m][b] += __shfl_xor(acc[m][b], 8);                                \
        acc[m][b] += __shfl_xor(acc[m][b], 16);                               \
        acc[m][b] += __shfl_xor(acc[m][b], 32);                               \
      }                                                                       \
    if (g == 0) {                                                             \
      _Pragma("unroll")                                                       \
      for (int m = 0; m < 4; ++m) {                                           \
        float* pp = &pA[(w * 32 + 4 * cq + m) * RS];                          \
        *(float4*)pp = make_float4(acc[m][0], acc[m][1], acc[m][2], acc[m][3]); \
        *(float4*)(pp + 4) = make_float4(acc[m][4], acc[m][5], acc[m][6], acc[m][7]); \
      }                                                                       \
    }                                                                         \
    __syncthreads();                                                          \
    {                                                                         \
      float s = pA[(0 * 32 + fc) * RS + fb] + pA[(1 * 32 + fc) * RS + fb] +   \
                pA[(2 * 32 + fc) * RS + fb] + pA[(3 * 32 + fc) * RS + fb] + biasA; \
      float sig = 1.0f / (1.0f + __expf(-s));                                 \
      if (fc < 16) {                                                          \
        float xo = BUF[(64 + 16 * cg + fc) * RS + fb];                        \
        float v = sig * xo;                                                   \
        float v1 = __shfl_xor(v, 1);                                          \
        if ((tid & 1) == 0)                                                   \
          gpubh(xfg + ((size_t)((BG) * H_) + 16 * cg + fc) * 4 + (fb >> 1),   \
                f2h2(v, v1));                                                 \
      } else {                                                                \
        ZREG = sig;                                                           \
        XOLDZ = BUF[(64 + 16 * cg + (fc - 16)) * RS + fb];                    \
      }                                                                       \
    }                                                                         \
    __syncthreads();                                                          \
    if (tid == 0) gaddu(CTRA, 1u);                                            \
    {                                                                         \
      float yp = 0.0f;                                                        \
      _Pragma("unroll")                                                       \
      for (int i = 0; i < 16; ++i)                                            \
        yp += wy[i] * BUF[(64 + yq + 32 * i) * RS + yb];                      \
      yp += __shfl_xor(yp, 1);  yp += __shfl_xor(yp, 2);                      \
      yp += __shfl_xor(yp, 4);  yp += __shfl_xor(yp, 8);                      \
      yp += __shfl_xor(yp, 16);                                               \
      if (yq == 0)                                                            \
        out[((size_t)((BG) * 8 + yb) * T_ + t) * OUT_ + cg] = yp + by;        \
    }                                                                         \
  }

#define PHASE_B(BG, BUF, ZREG, XOLDZ, CTRA, CTRB)                             \
  {                                                                           \
    if (!gbar_wait(CTRA, (unsigned)(NCG * (t + 1)), abort_w)) return;         \
    {                                                                         \
      const unsigned* s0 = xfg + ((size_t)((BG) * H_) + tid) * 4;             \
      const unsigned* s1 = xfg + ((size_t)((BG) * H_) + tid + 256) * 4;       \
      uint4 a, b;                                                             \
      gload2(s0, s1, a, b);                                                   \
      float2 c0 = h2f2(a.x), c1 = h2f2(a.y), c2 = h2f2(a.z), c3 = h2f2(a.w);  \
      *(float4*)&BUF[(64 + tid) * RS]     = make_float4(c0.x, c0.y, c1.x, c1.y); \
      *(float4*)&BUF[(64 + tid) * RS + 4] = make_float4(c2.x, c2.y, c3.x, c3.y); \
      float2 d0 = h2f2(b.x), d1 = h2f2(b.y), d2 = h2f2(b.z), d3 = h2f2(b.w);  \
      *(float4*)&BUF[(64 + tid + 256) * RS]     = make_float4(d0.x, d0.y, d1.x, d1.y); \
      *(float4*)&BUF[(64 + tid + 256) * RS + 4] = make_float4(d2.x, d2.y, d3.x, d3.y); \
    }                                                                         \
    __syncthreads();                                                          \
    float acc2[2][8] = {};                                                    \
    _Pragma("unroll")                                                         \
    for (int i = 0; i < KSL; ++i) {                                           \
      const float* xr = &BUF[(kb + i) * RS];                                  \
      float4 x0v = *(const float4*)xr;                                        \
      float4 x1v = *(const float4*)(xr + 4);                                  \
      _Pragma("unroll")                                                       \
      for (int m = 0; m < 2; ++m) {                                           \
        float wv = wB[i][m];                                                  \
        acc2[m][0] += wv * x0v.x; acc2[m][1] += wv * x0v.y;                   \
        acc2[m][2] += wv * x0v.z; acc2[m][3] += wv * x0v.w;                   \
        acc2[m][4] += wv * x1v.x; acc2[m][5] += wv * x1v.y;                   \
        acc2[m][6] += wv * x1v.z; acc2[m][7] += wv * x1v.w;                   \
      }                                                                       \
    }                                                                         \
    _Pragma("unroll")                                                         \
    for (int m = 0; m < 2; ++m)                                               \
      _Pragma("unroll")                                                       \
      for (int b = 0; b < 8; ++b) {                                           \
        acc2[m][b] += __shfl_xor(acc2[m][b], 8);                              \
        acc2[m][b] += __shfl_xor(acc2[m][b], 16);                             \
        acc2[m][b] += __shfl_xor(acc2[m][b], 32);                             \
      }                                                                       \
    if (g == 0) {                                                             \
      _Pragma("unroll")                                                       \
      for (int m = 0; m < 2; ++m) {                                           \
        float* pp = &pB[(w * 16 + 2 * cq + m) * RS];                          \
        *(float4*)pp = make_float4(acc2[m][0], acc2[m][1], acc2[m][2], acc2[m][3]); \
        *(float4*)(pp + 4) = make_float4(acc2[m][4], acc2[m][5], acc2[m][6], acc2[m][7]); \
      }                                                                       \
    }                                                                         \
    __syncthreads();                                                          \
    if (tid < 128) {                                                          \
      float s = pB[(0 * 16 + fc) * RS + fb] + pB[(1 * 16 + fc) * RS + fb] +   \
                pB[(2 * 16 + fc) * RS + fb] + pB[(3 * 16 + fc) * RS + fb] + biasB; \
      float e = __expf(2.0f * s);                                             \
      rbuf[fc * 8 + fb] = 1.0f - 2.0f / (1.0f + e);                           \
    }                                                                         \
    __syncthreads();                                                          \
    if (tid >= 128) {                                                         \
      float r = rbuf[(fc - 16) * 8 + fb];                                     \
      float xn = XOLDZ + ZREG * (r - XOLDZ);                                  \
      float xn1 = __shfl_xor(xn, 1);                                          \
      if ((tid & 1) == 0)                                                     \
        gpubh(xnxt + ((size_t)((BG) * H_) + 16 * cg + (fc - 16)) * 4 + (fb >> 1), \
              f2h2(xn, xn1));                                                 \
    }                                                                         \
    __syncthreads();                                                          \
    if (tid == 0) gaddu(CTRB, 1u);                                            \
    if (t + 1 < T_) {                                                         \
      int k2 = tid & 31, b = tid >> 5;                                        \
      float2 uv = *(const float2*)&u[((size_t)((BG) * 8 + b) * T_ + (t + 1)) * IN_ + 2 * k2]; \
      BUF[(2 * k2) * RS + b] = uv.x;                                          \
      BUF[(2 * k2 + 1) * RS + b] = uv.y;                                      \
    }                                                                         \
  }

__global__ __launch_bounds__(NTHR, 1) void gru_main(
    const float* __restrict__ u, const float* __restrict__ kfz,
    const float* __restrict__ bfz, const float* __restrict__ kr,
    const float* __restrict__ br, const float* __restrict__ wout,
    const float* __restrict__ bout, float* __restrict__ out, float* ws) {
  unsigned* wsu = (unsigned*)ws;
  unsigned* abort_w = wsu + ABORT_IDX;
  unsigned* xg0 = wsu + BUF_BASE;
  unsigned* xg1 = xg0 + XSLABW;
  unsigned* xfg = xg1 + XSLABW;

  const int bgp = blockIdx.x & 3;    // bg pair 0..3
  const int cg  = blockIdx.x >> 2;   // column group 0..31
  const int bg0 = 2 * bgp, bg1 = 2 * bgp + 1;
  const int tid = threadIdx.x;
  const int w   = tid >> 6;          // wave 0..3
  const int l   = tid & 63;
  const int cq  = l & 7;             // col-quad 0..7
  const int g   = l >> 3;            // in-wave k-slice 0..7
  const int kb  = (w * 8 + g) * KSL; // this thread's k base (18 k's)
  const int fc  = tid >> 3;          // finalize col 0..31
  const int fb  = tid & 7;           // finalize batch 0..7
  const int yb  = tid >> 5;          // y batch 0..7
  const int yq  = tid & 31;          // y k-slice 0..31

  unsigned* ctrA0 = wsu + CTR_OFF + (bg0 * 2 + 0) * CTR_STRIDE;
  unsigned* ctrB0 = wsu + CTR_OFF + (bg0 * 2 + 1) * CTR_STRIDE;
  unsigned* ctrA1 = wsu + CTR_OFF + (bg1 * 2 + 0) * CTR_STRIDE;
  unsigned* ctrB1 = wsu + CTR_OFF + (bg1 * 2 + 1) * CTR_STRIDE;

  __shared__ float buf0[KTOT * RS];  // bg0: [k][12]: u_t(k<64) | x or f*x
  __shared__ float buf1[KTOT * RS];  // bg1
  __shared__ float pA[4 * 32 * RS];  // shared across bgs (transient per slot)
  __shared__ float pB[4 * 16 * RS];
  __shared__ float rbuf[16 * 8];

  // ---- one-time: weights into registers (shared by both bgs) ----
  float wA[KSL][4];
#pragma unroll
  for (int i = 0; i < KSL; ++i)
#pragma unroll
    for (int m = 0; m < 4; ++m) {
      int c = 4 * cq + m;
      int gcol = (c < 16) ? (16 * cg + c) : (512 + 16 * cg + (c - 16));
      wA[i][m] = kfz[(size_t)(kb + i) * H2_ + gcol];
    }
  float wB[KSL][2];
#pragma unroll
  for (int i = 0; i < KSL; ++i)
#pragma unroll
    for (int m = 0; m < 2; ++m)
      wB[i][m] = kr[(size_t)(kb + i) * H_ + (16 * cg + 2 * cq + m)];
  float wy[16];
#pragma unroll
  for (int i = 0; i < 16; ++i) wy[i] = wout[cg * H_ + (yq + 32 * i)];
  const float by = bout[cg];
  const int fzc = (fc < 16) ? (16 * cg + fc) : (512 + 16 * cg + (fc - 16));
  const float biasA = bfz[fzc];
  const float biasB = (tid < 128) ? br[16 * cg + fc] : 0.0f;

  float zreg0 = 0.0f, xoldz0 = 0.0f;
  float zreg1 = 0.0f, xoldz1 = 0.0f;

  // u_t=0 into both buffers
  {
    int k2 = tid & 31, b = tid >> 5;
    float2 uv = *(const float2*)&u[((size_t)(bg0 * 8 + b) * T_) * IN_ + 2 * k2];
    buf0[(2 * k2) * RS + b] = uv.x;
    buf0[(2 * k2 + 1) * RS + b] = uv.y;
    float2 uw = *(const float2*)&u[((size_t)(bg1 * 8 + b) * T_) * IN_ + 2 * k2];
    buf1[(2 * k2) * RS + b] = uw.x;
    buf1[(2 * k2 + 1) * RS + b] = uw.y;
  }

  for (int t = 0; t < T_; ++t) {
    unsigned* xcur = (t & 1) ? xg1 : xg0;
    unsigned* xnxt = (t & 1) ? xg0 : xg1;

    PHASE_A(bg0, buf0, zreg0, xoldz0, ctrA0, ctrB0)
    PHASE_A(bg1, buf1, zreg1, xoldz1, ctrA1, ctrB1)
    PHASE_B(bg0, buf0, zreg0, xoldz0, ctrA0, ctrB0)
    PHASE_B(bg1, buf1, zreg1, xoldz1, ctrA1, ctrB1)
  }
}

extern "C" void kernel_launch(void* const* d_in, const int* in_sizes, int n_in,
                              void* d_out, int out_size, void* d_ws, size_t ws_size,
                              hipStream_t stream) {
  const float* u    = (const float*)d_in[0];
  const float* x0   = (const float*)d_in[1];
  const float* kfz  = (const float*)d_in[2];
  const float* bfz  = (const float*)d_in[3];
  const float* kr   = (const float*)d_in[4];
  const float* br   = (const float*)d_in[5];
  const float* wout = (const float*)d_in[6];
  const float* bout = (const float*)d_in[7];
  float* out = (float*)d_out;
  float* ws  = (float*)d_ws;

  hipLaunchKernelGGL(gru_init, dim3(64), dim3(256), 0, stream, ws, x0);
  hipLaunchKernelGGL(gru_main, dim3(4 * NCG), dim3(NTHR), 0, stream,
                     u, kfz, bfz, kr, br, wout, bout, out, ws);
}

// Round 11
// 14028.322 us; speedup vs baseline: 1.9913x; 1.9913x over previous
//
#include <hip/hip_runtime.h>
#include <hip/hip_fp16.h>
#include <stdint.h>

// Problem dims
#define B_    64
#define T_    2048
#define IN_   64
#define H_    512
#define H2_   1024
#define OUT_  32
#define KTOT  576          // IN_ + H_

// Grid: 256 blocks = 8 batch-groups x 32 col-groups, 256 threads.
// Critical path = ONE bg's chain: 2048 steps x 2 exchanges = 4096 MALL RTs
// (bgs already run concurrently on disjoint CUs -- round-10 proof that
// intra-block interleave of two domains just doubles barriers).
// This round: de-serialize the barrier. Round-4's single counter made 32
// blocks' atomic adds SERIALIZE on one word; now each block writes its OWN
// epoch flag (fire-and-forget, no contention), flags spread at 1KB stride
// (keeps round-4's channel-spreading win), and wave 0's 32 lanes poll all
// 32 flags with ONE vector load = one RT. Sleep-free spin (load-latency
// throttled).
#define NBG   8
#define NCG   32
#define NTHR  256
#define BPG   8            // batches per group
#define KSL   18           // k per slice (32 slices x 18 = 576)
#define RS    12           // bufA row stride in floats

// ws layout (32-bit words)
#define ABORT_IDX   0
#define FLAG_STRIDE 256                              // 1KB between flags
#define FLAGS_OFF   1024
#define FLAG_WORDS  (NBG * 2 * NCG * FLAG_STRIDE)    // 131072 words
#define BUF_BASE    (FLAGS_OFF + FLAG_WORDS)         // 132096 (64B-aligned)
#define XSLABW      16384    // words per fp16 slab: 8*512*8*2B / 4

// ---- fp16 pack/unpack ----
__device__ __forceinline__ unsigned f2h2(float a, float b) {
  __half2 h = __floats2half2_rn(a, b);   // lo = a, hi = b
  unsigned r; __builtin_memcpy(&r, &h, 4); return r;
}
__device__ __forceinline__ float2 h2f2(unsigned u) {
  __half2 h; __builtin_memcpy(&h, &u, 4);
  return __half22float2(h);              // x = lo, y = hi
}

// ---- MALL-resident exchange primitives ----
// Publish one packed (batch b, b+1) fp16 pair: 4B atomic swap, sc1 -> executed
// AT the MALL. Per-thread drain INSIDE (proven round-4/7 ordering:
// publish -> drain -> __syncthreads -> flag; independent work after flag).
__device__ __forceinline__ void gpubh(unsigned* p, unsigned v) {
  asm volatile("global_atomic_swap %0, %1, off sc1\n\ts_waitcnt vmcnt(0)"
               :: "v"(p), "v"(v) : "memory");
}
// Flag write: fire-and-forget 4B swap at the MALL (own slot, no contention).
__device__ __forceinline__ void gpubu(unsigned* p, unsigned v) {
  asm volatile("global_atomic_swap %0, %1, off sc1"
               :: "v"(p), "v"(v) : "memory");
}
// Coherent 4B poll load (bypasses stale L1/L2, reads the MALL).
__device__ __forceinline__ unsigned gpollu(const unsigned* p) {
  unsigned v;
  asm volatile("global_load_dword %0, %1, off sc0 sc1\n\ts_waitcnt vmcnt(0)"
               : "=v"(v) : "v"(p) : "memory");
  return v;
}
// Consume: two MALL-coherent 16B loads (one col x 8 batches fp16 each),
// both in flight, one wait -> one latency exposure per stage.
__device__ __forceinline__ void gload2(const unsigned* p0, const unsigned* p1,
                                       uint4& a, uint4& b) {
  asm volatile(
      "global_load_dwordx4 %0, %2, off sc0 sc1\n\t"
      "global_load_dwordx4 %1, %3, off sc0 sc1\n\t"
      "s_waitcnt vmcnt(0)"
      : "=&v"(a), "=&v"(b)
      : "v"(p0), "v"(p1)
      : "memory");
}

__global__ __launch_bounds__(256) void gru_init(float* ws, const float* __restrict__ x0) {
  int i = blockIdx.x * blockDim.x + threadIdx.x;
  int stride = gridDim.x * blockDim.x;
  unsigned* w = (unsigned*)ws;
  for (int k = i; k < BUF_BASE; k += stride) w[k] = 0u;   // abort + flags
  // xg0 slab (fp16): word p = (bg*512 + col)*4 + (b>>1)
  unsigned* xh = w + BUF_BASE;
  for (int p = i; p < NBG * H_ * 4; p += stride) {
    int bg = p >> 11, col = (p >> 2) & (H_ - 1), f2 = p & 3;
    float v0 = x0[(bg * 8 + 2 * f2) * H_ + col];
    float v1 = x0[(bg * 8 + 2 * f2 + 1) * H_ + col];
    xh[p] = f2h2(v0, v1);
  }
}

// Wait: 32 lanes of wave 0 poll 32 DISTINCT 1KB-strided flags in parallel
// (one load instruction -> one RT for the whole fan-in; no add serialization).
// Sleep-free: the ~600cy load RT throttles the loop naturally.
__device__ __forceinline__ bool gbar_wait(unsigned* base, unsigned target,
                                          unsigned* abort_w) {
  __shared__ int s_ok;
  const int tid = threadIdx.x;
  int ok = 1;
  if (tid < NCG) {
    const unsigned* f = base + tid * FLAG_STRIDE;
    int polls = 0;
    while (gpollu(f) < target) {
      if ((++polls & 255) == 0) {
        if (__hip_atomic_load(abort_w, __ATOMIC_RELAXED, __HIP_MEMORY_SCOPE_AGENT) != 0u ||
            polls > 4000000) {
          __hip_atomic_store(abort_w, 1u, __ATOMIC_RELAXED, __HIP_MEMORY_SCOPE_AGENT);
          ok = 0;
          break;
        }
      }
    }
  }
  if (tid < 64) {
    unsigned long long bad = __ballot(ok == 0);
    if (tid == 0) s_ok = (bad == 0ull) ? 1 : 0;
  }
  __syncthreads();
  __atomic_signal_fence(__ATOMIC_ACQUIRE);  // compiler reordering guard only
  return s_ok != 0;
}

__global__ __launch_bounds__(NTHR, 1) void gru_main(
    const float* __restrict__ u, const float* __restrict__ kfz,
    const float* __restrict__ bfz, const float* __restrict__ kr,
    const float* __restrict__ br, const float* __restrict__ wout,
    const float* __restrict__ bout, float* __restrict__ out, float* ws) {
  unsigned* wsu = (unsigned*)ws;
  unsigned* abort_w = wsu + ABORT_IDX;
  unsigned* flags = wsu + FLAGS_OFF;
  unsigned* xg0 = wsu + BUF_BASE;
  unsigned* xg1 = xg0 + XSLABW;
  unsigned* xfg = xg1 + XSLABW;

  const int bg  = blockIdx.x & 7;
  const int cg  = blockIdx.x >> 3;   // column group 0..31
  const int tid = threadIdx.x;
  const int w   = tid >> 6;          // wave 0..3
  const int l   = tid & 63;
  const int cq  = l & 7;             // col-quad 0..7
  const int g   = l >> 3;            // in-wave k-slice 0..7
  const int kb  = (w * 8 + g) * KSL; // this thread's k base (18 k's)
  const int fc  = tid >> 3;          // finalize col 0..31
  const int fb  = tid & 7;           // finalize batch 0..7
  const int yb  = tid >> 5;          // y batch 0..7
  const int yq  = tid & 31;          // y k-slice 0..31

  unsigned* slotA = flags + ((bg * 2 + 0) * NCG + cg) * FLAG_STRIDE;
  unsigned* slotB = flags + ((bg * 2 + 1) * NCG + cg) * FLAG_STRIDE;
  unsigned* baseA = flags + (bg * 2 + 0) * NCG * FLAG_STRIDE;
  unsigned* baseB = flags + (bg * 2 + 1) * NCG * FLAG_STRIDE;

  __shared__ float bufA[KTOT * RS];  // [k][12]: u_t(k<64) | x or f*x
  __shared__ float pA[4 * 32 * RS];
  __shared__ float pB[4 * 16 * RS];
  __shared__ float rbuf[16 * 8];

  // ---- one-time: weights into registers ----
  float wA[KSL][4];
#pragma unroll
  for (int i = 0; i < KSL; ++i)
#pragma unroll
    for (int m = 0; m < 4; ++m) {
      int c = 4 * cq + m;
      int gcol = (c < 16) ? (16 * cg + c) : (512 + 16 * cg + (c - 16));
      wA[i][m] = kfz[(size_t)(kb + i) * H2_ + gcol];
    }
  float wB[KSL][2];
#pragma unroll
  for (int i = 0; i < KSL; ++i)
#pragma unroll
    for (int m = 0; m < 2; ++m)
      wB[i][m] = kr[(size_t)(kb + i) * H_ + (16 * cg + 2 * cq + m)];
  float wy[16];
#pragma unroll
  for (int i = 0; i < 16; ++i) wy[i] = wout[cg * H_ + (yq + 32 * i)];
  const float by = bout[cg];
  const int fzc = (fc < 16) ? (16 * cg + fc) : (512 + 16 * cg + (fc - 16));
  const float biasA = bfz[fzc];
  const float biasB = (tid < 128) ? br[16 * cg + fc] : 0.0f;

  float zreg = 0.0f, xoldz = 0.0f;

  // u_t=0 into LDS (later steps prefetched during barrier-B window)
  {
    int k2 = tid & 31, b = tid >> 5;
    float2 uv = *(const float2*)&u[((size_t)(bg * 8 + b) * T_) * IN_ + 2 * k2];
    bufA[(2 * k2) * RS + b] = uv.x;
    bufA[(2 * k2 + 1) * RS + b] = uv.y;
  }

  for (int t = 0; t < T_; ++t) {
    unsigned* xcur = (t & 1) ? xg1 : xg0;
    unsigned* xnxt = (t & 1) ? xg0 : xg1;

    // ---- stage x into bufA (fp16 slab: 2 cols/thread, cvt, b128 writes) ----
    {
      const unsigned* s0 = xcur + ((size_t)(bg * H_) + tid) * 4;
      const unsigned* s1 = xcur + ((size_t)(bg * H_) + tid + 256) * 4;
      uint4 a, b;
      gload2(s0, s1, a, b);
      float2 c0 = h2f2(a.x), c1 = h2f2(a.y), c2 = h2f2(a.z), c3 = h2f2(a.w);
      *(float4*)&bufA[(64 + tid) * RS]     = make_float4(c0.x, c0.y, c1.x, c1.y);
      *(float4*)&bufA[(64 + tid) * RS + 4] = make_float4(c2.x, c2.y, c3.x, c3.y);
      float2 d0 = h2f2(b.x), d1 = h2f2(b.y), d2 = h2f2(b.z), d3 = h2f2(b.w);
      *(float4*)&bufA[(64 + tid + 256) * RS]     = make_float4(d0.x, d0.y, d1.x, d1.y);
      *(float4*)&bufA[(64 + tid + 256) * RS + 4] = make_float4(d2.x, d2.y, d3.x, d3.y);
    }
    __syncthreads();

    // ---- phase A core: fz partials for 4 cols x 8 batches over 18 k ----
    float acc[4][8] = {};
#pragma unroll
    for (int i = 0; i < KSL; ++i) {
      const float* xr = &bufA[(kb + i) * RS];
      float4 x0 = *(const float4*)xr;
      float4 x1 = *(const float4*)(xr + 4);
#pragma unroll
      for (int m = 0; m < 4; ++m) {
        float wv = wA[i][m];
        acc[m][0] += wv * x0.x; acc[m][1] += wv * x0.y;
        acc[m][2] += wv * x0.z; acc[m][3] += wv * x0.w;
        acc[m][4] += wv * x1.x; acc[m][5] += wv * x1.y;
        acc[m][6] += wv * x1.z; acc[m][7] += wv * x1.w;
      }
    }

    // ---- reduce A ----
#pragma unroll
    for (int m = 0; m < 4; ++m)
#pragma unroll
      for (int b = 0; b < 8; ++b) {
        acc[m][b] += __shfl_xor(acc[m][b], 8);
        acc[m][b] += __shfl_xor(acc[m][b], 16);
        acc[m][b] += __shfl_xor(acc[m][b], 32);
      }
    if (g == 0) {
#pragma unroll
      for (int m = 0; m < 4; ++m) {
        float* p = &pA[(w * 32 + 4 * cq + m) * RS];
        *(float4*)p = make_float4(acc[m][0], acc[m][1], acc[m][2], acc[m][3]);
        *(float4*)(p + 4) = make_float4(acc[m][4], acc[m][5], acc[m][6], acc[m][7]);
      }
    }
    __syncthreads();

    // ---- finalize A: sigmoid; publish packed fp16 f*x pairs; stash z ----
    {
      float s = pA[(0 * 32 + fc) * RS + fb] + pA[(1 * 32 + fc) * RS + fb] +
                pA[(2 * 32 + fc) * RS + fb] + pA[(3 * 32 + fc) * RS + fb] + biasA;
      float sig = 1.0f / (1.0f + __expf(-s));
      if (fc < 16) {
        float xo = bufA[(64 + 16 * cg + fc) * RS + fb];
        float v = sig * xo;
        float v1 = __shfl_xor(v, 1);      // neighbor batch's value
        if ((tid & 1) == 0) {
          unsigned* p = xfg + ((size_t)(bg * H_) + 16 * cg + fc) * 4 + (fb >> 1);
          gpubh(p, f2h2(v, v1));          // swap + drain
        }
      } else {
        zreg = sig;
        xoldz = bufA[(64 + 16 * cg + (fc - 16)) * RS + fb];
      }
    }

    // publishes drained per-thread -> sync -> own flag (no contention)
    __syncthreads();
    if (tid == 0) gpubu(slotA, (unsigned)(t + 1));

    // ---- y_t = x_t @ wout[cg]: overlaps the barrier poll ----
    {
      float yp = 0.0f;
#pragma unroll
      for (int i = 0; i < 16; ++i)
        yp += wy[i] * bufA[(64 + yq + 32 * i) * RS + yb];
      yp += __shfl_xor(yp, 1);  yp += __shfl_xor(yp, 2);
      yp += __shfl_xor(yp, 4);  yp += __shfl_xor(yp, 8);
      yp += __shfl_xor(yp, 16);
      if (yq == 0)
        out[((size_t)(bg * 8 + yb) * T_ + t) * OUT_ + cg] = yp + by;
    }

    if (!gbar_wait(baseA, (unsigned)(t + 1), abort_w)) return;

    // ---- stage f*x into bufA (fp16 slab) ----
    {
      const unsigned* s0 = xfg + ((size_t)(bg * H_) + tid) * 4;
      const unsigned* s1 = xfg + ((size_t)(bg * H_) + tid + 256) * 4;
      uint4 a, b;
      gload2(s0, s1, a, b);
      float2 c0 = h2f2(a.x), c1 = h2f2(a.y), c2 = h2f2(a.z), c3 = h2f2(a.w);
      *(float4*)&bufA[(64 + tid) * RS]     = make_float4(c0.x, c0.y, c1.x, c1.y);
      *(float4*)&bufA[(64 + tid) * RS + 4] = make_float4(c2.x, c2.y, c3.x, c3.y);
      float2 d0 = h2f2(b.x), d1 = h2f2(b.y), d2 = h2f2(b.z), d3 = h2f2(b.w);
      *(float4*)&bufA[(64 + tid + 256) * RS]     = make_float4(d0.x, d0.y, d1.x, d1.y);
      *(float4*)&bufA[(64 + tid + 256) * RS + 4] = make_float4(d2.x, d2.y, d3.x, d3.y);
    }
    __syncthreads();

    // ---- phase B core: r partials for 2 cols x 8 batches ----
    float acc2[2][8] = {};
#pragma unroll
    for (int i = 0; i < KSL; ++i) {
      const float* xr = &bufA[(kb + i) * RS];
      float4 x0 = *(const float4*)xr;
      float4 x1 = *(const float4*)(xr + 4);
#pragma unroll
      for (int m = 0; m < 2; ++m) {
        float wv = wB[i][m];
        acc2[m][0] += wv * x0.x; acc2[m][1] += wv * x0.y;
        acc2[m][2] += wv * x0.z; acc2[m][3] += wv * x0.w;
        acc2[m][4] += wv * x1.x; acc2[m][5] += wv * x1.y;
        acc2[m][6] += wv * x1.z; acc2[m][7] += wv * x1.w;
      }
    }
#pragma unroll
    for (int m = 0; m < 2; ++m)
#pragma unroll
      for (int b = 0; b < 8; ++b) {
        acc2[m][b] += __shfl_xor(acc2[m][b], 8);
        acc2[m][b] += __shfl_xor(acc2[m][b], 16);
        acc2[m][b] += __shfl_xor(acc2[m][b], 32);
      }
    if (g == 0) {
#pragma unroll
      for (int m = 0; m < 2; ++m) {
        float* p = &pB[(w * 16 + 2 * cq + m) * RS];
        *(float4*)p = make_float4(acc2[m][0], acc2[m][1], acc2[m][2], acc2[m][3]);
        *(float4*)(p + 4) = make_float4(acc2[m][4], acc2[m][5], acc2[m][6], acc2[m][7]);
      }
    }
    __syncthreads();

    // ---- finalize B: tanh -> rbuf ----
    if (tid < 128) {
      float s = pB[(0 * 16 + fc) * RS + fb] + pB[(1 * 16 + fc) * RS + fb] +
                pB[(2 * 16 + fc) * RS + fb] + pB[(3 * 16 + fc) * RS + fb] + biasB;
      float e = __expf(2.0f * s);
      rbuf[fc * 8 + fb] = 1.0f - 2.0f / (1.0f + e);
    }
    __syncthreads();

    // ---- update: x_next = x + z*(r - x); packed fp16 publish ----
    if (tid >= 128) {
      float r = rbuf[(fc - 16) * 8 + fb];
      float xn = xoldz + zreg * (r - xoldz);
      float xn1 = __shfl_xor(xn, 1);
      if ((tid & 1) == 0) {
        unsigned* p = xnxt + ((size_t)(bg * H_) + 16 * cg + (fc - 16)) * 4 + (fb >> 1);
        gpubh(p, f2h2(xn, xn1));          // swap + drain
      }
    }

    // publishes drained -> sync -> own flag; u-prefetch AFTER the flag
    __syncthreads();
    if (tid == 0) gpubu(slotB, (unsigned)(t + 1));

    // ---- prefetch u_{t+1} into LDS while barrier-B resolves ----
    if (t + 1 < T_) {
      int k2 = tid & 31, b = tid >> 5;
      float2 uv = *(const float2*)&u[((size_t)(bg * 8 + b) * T_ + (t + 1)) * IN_ + 2 * k2];
      bufA[(2 * k2) * RS + b] = uv.x;
      bufA[(2 * k2 + 1) * RS + b] = uv.y;
    }

    if (!gbar_wait(baseB, (unsigned)(t + 1), abort_w)) return;
  }
}

extern "C" void kernel_launch(void* const* d_in, const int* in_sizes, int n_in,
                              void* d_out, int out_size, void* d_ws, size_t ws_size,
                              hipStream_t stream) {
  const float* u    = (const float*)d_in[0];
  const float* x0   = (const float*)d_in[1];
  const float* kfz  = (const float*)d_in[2];
  const float* bfz  = (const float*)d_in[3];
  const float* kr   = (const float*)d_in[4];
  const float* br   = (const float*)d_in[5];
  const float* wout = (const float*)d_in[6];
  const float* bout = (const float*)d_in[7];
  float* out = (float*)d_out;
  float* ws  = (float*)d_ws;

  hipLaunchKernelGGL(gru_init, dim3(64), dim3(256), 0, stream, ws, x0);
  hipLaunchKernelGGL(gru_main, dim3(NBG * NCG), dim3(NTHR), 0, stream,
                     u, kfz, bfz, kr, br, wout, bout, out, ws);
}